// Round 10
// baseline (512.161 us; speedup 1.0000x reference)
//
#include <hip/hip_runtime.h>

// ---------------------------------------------------------------------------
// ResBlock GNN layer on MI355X (gfx950). ALL tensors fp32.
//   h  = gelu(x @ W_ff1 + b)
//   h += seg_sum(gelu(P[src]+Q[dst]+R_e+b_mp)), P=h@Wa, Q=h@Wb, R=ef@Wc  (x2)
//   out = x + h @ W_ff2 + b
// R16: front-matter fusion. fused_kernel = R15 verbatim (proven 92us).
//  - ffn1pq_kernel: FFN1 + P/Q-GEMM in ONE kernel. 1-wave blocks (64 thr,
//    16 rows, 625 blocks -> max spread, no barriers). h-tile lives in 8.4 KB
//    LDS (bf16, +8 pad); same-wave write->read needs no syncthreads. A-frag
//    cached in regs (short8 x8) and reused for P and Q passes.
//  - pq2_kernel: P/Q for layer 2 reading Hacc f32 directly (converts in
//    flight) -> finalize_h dispatch and h_bf buffer DELETED entirely.
//  - 12 -> 10 dispatches; h_bf HBM round-trips gone.
// ---------------------------------------------------------------------------

typedef __attribute__((ext_vector_type(8))) short short8;
typedef __attribute__((ext_vector_type(4))) float f32x4;

#define HD __device__ __forceinline__

HD unsigned short f2bf(float f) {
    unsigned int u = __float_as_uint(f);
    return (unsigned short)((u + 0x7fffu + ((u >> 16) & 1u)) >> 16);  // RNE
}
HD float lo16(unsigned int u) { return __uint_as_float(u << 16); }
HD float hi16(unsigned int u) { return __uint_as_float(u & 0xffff0000u); }
HD float bf2f(unsigned short u) { return __uint_as_float(((unsigned int)u) << 16); }

// gelu tanh-approx via sigmoid identity: 0.5(1+tanh(z)) == sigmoid(2z).
HD float gelu_f(float x) {
    float u = x * (-1.5957691216057308f - 0.07135481627f * (x * x));
    return x * __builtin_amdgcn_rcpf(1.f + __expf(u));
}

// ---------------------------------------------------------------------------
// All 8 weight repacks in one dispatch.
// ---------------------------------------------------------------------------
__global__ void repack_all(const float* __restrict__ Wff1,
                           const float* __restrict__ Wmp1,
                           const float* __restrict__ Wmp2,
                           const float* __restrict__ Wff2,
                           unsigned short* __restrict__ Bp) {
    const int begs[9] = {0, 65536, 131072, 196608, 212992, 278528, 344064,
                         360448, 425984};
    const int srcid[8] = {0, 1, 1, 1, 2, 2, 2, 3};
    const int rowoff[8] = {0, 0, 256, 512, 0, 256, 512, 0};
    int i = blockIdx.x * 256 + threadIdx.x;
    if (i >= 425984) return;
    int s = 0;
#pragma unroll
    for (int k = 1; k < 8; ++k)
        if (i >= begs[k]) s = k;
    const float* Ws[4] = {Wff1, Wmp1, Wmp2, Wff2};
    const float* B = Ws[srcid[s]];
    int local = i - begs[s];
    int k = local >> 8, n = local & 255;
    int kb = k >> 5, kr = k & 31;
    int quad = kr >> 3, j = kr & 7;
    int lane = quad * 16 + (n & 15);
    int nt = n >> 4;
    Bp[begs[s] + ((((kb * 16 + nt) * 64) + lane) << 3) + j] =
        f2bf(B[(size_t)(rowoff[s] + k) * 256 + n]);
}

// ---------------------------------------------------------------------------
// General LDS-free bf16 MFMA GEMM (64x64 tile, grid (ceil(M/64),4)); FFN2.
// ---------------------------------------------------------------------------
__global__ __launch_bounds__(256) void gemm_kernel(
    const void* __restrict__ Av, int a_is_f32, int M, int K,
    const unsigned short* __restrict__ Bp,
    const float* __restrict__ bias, const float* __restrict__ resid,
    unsigned short* __restrict__ Cb, float* __restrict__ Cf, int do_gelu) {
    int lane = threadIdx.x & 63;
    int w = threadIdx.x >> 6;
    int row0 = blockIdx.x * 64 + w * 16;
    int n0 = blockIdx.y * 64;
    int m15 = lane & 15, quad = lane >> 4;

    int arow = row0 + m15;
    if (arow > M - 1) arow = M - 1;

    f32x4 acc[4] = {{0,0,0,0},{0,0,0,0},{0,0,0,0},{0,0,0,0}};
    const float* Af = (const float*)Av + (size_t)arow * K + quad * 8;
    const unsigned short* Ab = (const unsigned short*)Av + (size_t)arow * K + quad * 8;

    for (int kt = 0; kt < K; kt += 32) {
        short8 a;
        if (a_is_f32) {
            f32x4 lo = *(const f32x4*)(Af + kt);
            f32x4 hi = *(const f32x4*)(Af + kt + 4);
#pragma unroll
            for (int j = 0; j < 4; ++j) {
                a[j] = (short)f2bf(lo[j]);
                a[j + 4] = (short)f2bf(hi[j]);
            }
        } else {
            a = *(const short8*)(Ab + kt);
        }
        const unsigned short* bbase =
            Bp + ((((size_t)(kt >> 5) * 16 + (n0 >> 4)) * 64 + lane) << 3);
#pragma unroll
        for (int nt = 0; nt < 4; ++nt) {
            short8 b = *(const short8*)(bbase + nt * 64 * 8);
            acc[nt] = __builtin_amdgcn_mfma_f32_16x16x32_bf16(a, b, acc[nt], 0, 0, 0);
        }
    }

#pragma unroll
    for (int nt = 0; nt < 4; ++nt) {
        int col = n0 + nt * 16 + m15;
        float bv = bias ? bias[col] : 0.f;
#pragma unroll
        for (int r = 0; r < 4; ++r) {
            int row = row0 + quad * 4 + r;
            if (row < M) {
                float v = acc[nt][r] + bv;
                if (do_gelu) v = gelu_f(v);
                size_t idx = (size_t)row * 256 + col;
                if (resid) v += resid[idx];
                if (Cb) Cb[idx] = f2bf(v);
                if (Cf) Cf[idx] = v;
            }
        }
    }
}

// ---------------------------------------------------------------------------
// ffn1pq: one wave per 16 rows. Pass 1: h = gelu(x@Wff1+b) -> Hacc f32 +
// LDS bf16. Pass 2: P = h@Wa. Pass 3: Q = h@Wb + b_mp. A-frag cached in regs.
// ---------------------------------------------------------------------------
__global__ __launch_bounds__(64) void ffn1pq_kernel(
    const float* __restrict__ x, const unsigned short* __restrict__ BpF,
    const float* __restrict__ bff1,
    const unsigned short* __restrict__ BpA, const unsigned short* __restrict__ BpB,
    const float* __restrict__ qbias, float* __restrict__ Hacc,
    unsigned short* __restrict__ Pb, unsigned short* __restrict__ Qb, int M) {
    __shared__ unsigned short hl[16 * 264];  // 8.4 KB, +8 pad per row
    int lane = threadIdx.x;
    int m15 = lane & 15, quad = lane >> 4;
    int row0 = blockIdx.x * 16;

    // ---- pass 1: h-tile ----
    int arow = row0 + m15;
    if (arow > M - 1) arow = M - 1;
    const float* Af = x + (size_t)arow * 256 + quad * 8;

    f32x4 acc[16];
#pragma unroll
    for (int nt = 0; nt < 16; ++nt) acc[nt] = {0.f, 0.f, 0.f, 0.f};
#pragma unroll
    for (int kt = 0; kt < 256; kt += 32) {
        f32x4 lo = *(const f32x4*)(Af + kt);
        f32x4 hi = *(const f32x4*)(Af + kt + 4);
        short8 a;
#pragma unroll
        for (int j = 0; j < 4; ++j) {
            a[j] = (short)f2bf(lo[j]);
            a[j + 4] = (short)f2bf(hi[j]);
        }
        const unsigned short* bb = BpF + ((((size_t)(kt >> 5) * 16) * 64 + lane) << 3);
#pragma unroll
        for (int nt = 0; nt < 16; ++nt) {
            short8 b = *(const short8*)(bb + (size_t)nt * 64 * 8);
            acc[nt] = __builtin_amdgcn_mfma_f32_16x16x32_bf16(a, b, acc[nt], 0, 0, 0);
        }
    }
#pragma unroll
    for (int nt = 0; nt < 16; ++nt) {
        int col = nt * 16 + m15;
        float bv = bff1[col];
#pragma unroll
        for (int r = 0; r < 4; ++r) {
            int lrow = quad * 4 + r;
            float v = gelu_f(acc[nt][r] + bv);
            if (row0 + lrow < M) Hacc[(size_t)(row0 + lrow) * 256 + col] = v;
            hl[lrow * 264 + col] = f2bf(v);
        }
    }
    // same-wave LDS write->read: compiler orders via lgkmcnt, no barrier.

    // cache A-fragments (rows m15, cols quad*8+kt..+8) in regs
    short8 afrag[8];
#pragma unroll
    for (int kt8 = 0; kt8 < 8; ++kt8)
        afrag[kt8] = *(const short8*)(hl + m15 * 264 + quad * 8 + kt8 * 32);

    // ---- passes 2/3: P then Q ----
#pragma unroll
    for (int pass = 0; pass < 2; ++pass) {
        const unsigned short* Bw = pass ? BpB : BpA;
        unsigned short* out = pass ? Qb : Pb;
#pragma unroll
        for (int nt = 0; nt < 16; ++nt) acc[nt] = {0.f, 0.f, 0.f, 0.f};
#pragma unroll
        for (int kt8 = 0; kt8 < 8; ++kt8) {
            const unsigned short* bb =
                Bw + ((((size_t)(kt8 >> 1) * 16) * 64 + lane) << 3) + (kt8 & 1) * 0;
            // NOTE: kt = kt8*32; (kt>>5) == kt8
            bb = Bw + ((((size_t)kt8 * 16) * 64 + lane) << 3);
#pragma unroll
            for (int nt = 0; nt < 16; ++nt) {
                short8 b = *(const short8*)(bb + (size_t)nt * 64 * 8);
                acc[nt] = __builtin_amdgcn_mfma_f32_16x16x32_bf16(afrag[kt8], b,
                                                                  acc[nt], 0, 0, 0);
            }
        }
#pragma unroll
        for (int nt = 0; nt < 16; ++nt) {
            int col = nt * 16 + m15;
            float bv = pass ? qbias[col] : 0.f;
#pragma unroll
            for (int r = 0; r < 4; ++r) {
                int row = row0 + quad * 4 + r;
                if (row < M) out[(size_t)row * 256 + col] = f2bf(acc[nt][r] + bv);
            }
        }
    }
}

// ---------------------------------------------------------------------------
// pq2: P/Q from f32 Hacc (converts in flight; replaces finalize_h + pq).
// ---------------------------------------------------------------------------
__global__ __launch_bounds__(64) void pq2_kernel(
    const float* __restrict__ Hin,
    const unsigned short* __restrict__ BpA, const unsigned short* __restrict__ BpB,
    const float* __restrict__ qbias,
    unsigned short* __restrict__ Pb, unsigned short* __restrict__ Qb, int M) {
    int lane = threadIdx.x;
    int m15 = lane & 15, quad = lane >> 4;
    int row0 = blockIdx.x * 16;
    int arow = row0 + m15;
    if (arow > M - 1) arow = M - 1;
    const float* Af = Hin + (size_t)arow * 256 + quad * 8;

    short8 afrag[8];
#pragma unroll
    for (int kt8 = 0; kt8 < 8; ++kt8) {
        f32x4 lo = *(const f32x4*)(Af + kt8 * 32);
        f32x4 hi = *(const f32x4*)(Af + kt8 * 32 + 4);
        short8 a;
#pragma unroll
        for (int j = 0; j < 4; ++j) {
            a[j] = (short)f2bf(lo[j]);
            a[j + 4] = (short)f2bf(hi[j]);
        }
        afrag[kt8] = a;
    }

    f32x4 acc[16];
#pragma unroll
    for (int pass = 0; pass < 2; ++pass) {
        const unsigned short* Bw = pass ? BpB : BpA;
        unsigned short* out = pass ? Qb : Pb;
#pragma unroll
        for (int nt = 0; nt < 16; ++nt) acc[nt] = {0.f, 0.f, 0.f, 0.f};
#pragma unroll
        for (int kt8 = 0; kt8 < 8; ++kt8) {
            const unsigned short* bb = Bw + ((((size_t)kt8 * 16) * 64 + lane) << 3);
#pragma unroll
            for (int nt = 0; nt < 16; ++nt) {
                short8 b = *(const short8*)(bb + (size_t)nt * 64 * 8);
                acc[nt] = __builtin_amdgcn_mfma_f32_16x16x32_bf16(afrag[kt8], b,
                                                                  acc[nt], 0, 0, 0);
            }
        }
#pragma unroll
        for (int nt = 0; nt < 16; ++nt) {
            int col = nt * 16 + m15;
            float bv = pass ? qbias[col] : 0.f;
#pragma unroll
            for (int r = 0; r < 4; ++r) {
                int row = row0 + quad * 4 + r;
                if (row < M) out[(size_t)row * 256 + col] = f2bf(acc[nt][r] + bv);
            }
        }
    }
}

// ---------------------------------------------------------------------------
// Counting sort by dst: zero -> histogram -> single-block scan -> scatter.
// ---------------------------------------------------------------------------
__global__ void zero_i32(int* __restrict__ p, int n) {
    int i = blockIdx.x * 256 + threadIdx.x;
    if (i < n) p[i] = 0;
}
__global__ void hist_kernel(const int* __restrict__ dst, int* __restrict__ cnt, int E) {
    int e = blockIdx.x * 256 + threadIdx.x;
    if (e < E) atomicAdd(&cnt[dst[e]], 1);
}
__global__ __launch_bounds__(1024) void scan_kernel(const int* __restrict__ cnt,
                                                    int* __restrict__ cursor, int N) {
    __shared__ int part[1024];
    int tid = threadIdx.x;
    int per = (N + 1023) / 1024;
    int lo = tid * per;
    int s = 0;
    for (int j = 0; j < per; ++j) {
        int idx = lo + j;
        if (idx < N) s += cnt[idx];
    }
    part[tid] = s;
    __syncthreads();
    for (int off = 1; off < 1024; off <<= 1) {
        int t = (tid >= off) ? part[tid - off] : 0;
        __syncthreads();
        part[tid] += t;
        __syncthreads();
    }
    int run = (tid > 0) ? part[tid - 1] : 0;
    for (int j = 0; j < per; ++j) {
        int idx = lo + j;
        if (idx < N) {
            cursor[idx] = run;
            run += cnt[idx];
        }
    }
}
__global__ void scatter_kernel(const int* __restrict__ src, const int* __restrict__ dst,
                               int* __restrict__ cursor, int* __restrict__ perm,
                               int* __restrict__ srcs, int* __restrict__ dsts, int E) {
    int e = blockIdx.x * 256 + threadIdx.x;
    if (e < E) {
        int d = dst[e];
        int pos = atomicAdd(&cursor[d], 1);
        perm[pos] = e;
        srcs[pos] = src[e];
        dsts[pos] = d;
    }
}

// ---------------------------------------------------------------------------
// FUSED edge kernel (R15, unchanged). Block = 256 thr = one 64-edge tile.
// ---------------------------------------------------------------------------
__global__ __launch_bounds__(256, 4) void fused_kernel(
    const float* __restrict__ ef, const int* __restrict__ perm,
    const int* __restrict__ srcs, const int* __restrict__ dsts,
    const unsigned short* __restrict__ BpC,
    const unsigned short* __restrict__ Pb, const unsigned short* __restrict__ Qb,
    const int* __restrict__ cursor, const int* __restrict__ cnt,
    float* __restrict__ Hacc, int E) {
    __shared__ unsigned short tiles[64 * 256];  // 32 KB R tile (swizzled)
    float* Fr = (float*)tiles;            // [4][256] carry (aliased later)
    float* Lr = Fr + 4 * 256;             // [4][256]
    int* Cd = (int*)(Lr + 4 * 256);       // [8]

    int lane = threadIdx.x & 63;
    int w = threadIdx.x >> 6;  // 0..3
    int e_lo = blockIdx.x * 64;
    int n_e = E - e_lo;
    if (n_e > 64) n_e = 64;
    int e_hi = e_lo + n_e;
    int base = w * 16;
    int m15 = lane & 15, quad = lane >> 4;
    int c0 = lane << 2;

    int myi = base + (lane & 15);
    int mye = e_lo + myi;
    if (mye > E - 1) mye = E - 1;
    int vsw = srcs[mye];
    int vdw = dsts[mye];

    int cur_d = -2;
    uint2 qu = {0u, 0u};
    if (base < n_e) {
        cur_d = __builtin_amdgcn_readlane(vdw, 0);
        qu = *(const uint2*)(Qb + (((size_t)cur_d) << 8) + c0);
    }
    int fd_first = cur_d;

    // ---- Phase 1: rgemm body, wave w -> rows base..base+15 ----
    {
        int ar = e_lo + base + m15;
        if (ar > E - 1) ar = E - 1;
        int g = perm[ar];
        const float* A = ef + (size_t)g * 64 + quad * 8;

        f32x4 acc[16];
#pragma unroll
        for (int i = 0; i < 16; ++i) acc[i] = {0.f, 0.f, 0.f, 0.f};

#pragma unroll
        for (int kb = 0; kb < 2; ++kb) {
            f32x4 lo = *(const f32x4*)(A + kb * 32);
            f32x4 hi = *(const f32x4*)(A + kb * 32 + 4);
            short8 a;
#pragma unroll
            for (int j = 0; j < 4; ++j) {
                a[j] = (short)f2bf(lo[j]);
                a[j + 4] = (short)f2bf(hi[j]);
            }
            const unsigned short* bb = BpC + (((size_t)kb * 16 * 64 + lane) << 3);
#pragma unroll
            for (int nt = 0; nt < 16; ++nt) {
                short8 b = *(const short8*)(bb + (size_t)nt * 64 * 8);
                acc[nt] = __builtin_amdgcn_mfma_f32_16x16x32_bf16(a, b, acc[nt], 0, 0, 0);
            }
        }

#pragma unroll
        for (int nt = 0; nt < 16; ++nt) {
            int colp = ((nt ^ quad) << 4) + m15;
#pragma unroll
            for (int r = 0; r < 4; ++r) {
                int row = base + quad * 4 + r;
                tiles[row * 256 + colp] = f2bf(acc[nt][r]);
            }
        }
    }
    // NO barrier: wave w's phase 2 reads only rows it wrote itself.

    // ---- Phase 2: walk own 16 rows, 4 ch/lane ----
    float s0 = 0.f, s1 = 0.f, s2 = 0.f, s3 = 0.f;
    float F0 = 0.f, F1 = 0.f, F2 = 0.f, F3 = 0.f;
    int lastd = -2;
    int emitted = 0;

    if (n_e == 64) {
        uint2 pu[16], ru[16];
#pragma unroll
        for (int j = 0; j < 16; ++j) {
            int s = __builtin_amdgcn_readlane(vsw, j);
            pu[j] = *(const uint2*)(Pb + (((size_t)s) << 8) + c0);
            int k = base + j;
            int off = (((lane >> 2) ^ ((j >> 2) & 3)) << 4) + ((lane & 3) << 2);
            ru[j] = *(const uint2*)(tiles + k * 256 + off);
        }
#pragma unroll
        for (int j = 0; j < 16; ++j) {
            if (j > 0) {
                int d = __builtin_amdgcn_readlane(vdw, j);
                if (d != cur_d) {
                    if (!emitted) {
                        F0 = s0; F1 = s1; F2 = s2; F3 = s3;
                        emitted = 1;
                    } else {
                        float* hp = Hacc + (((size_t)cur_d) << 8) + c0;
                        hp[0] += s0; hp[1] += s1; hp[2] += s2; hp[3] += s3;
                    }
                    s0 = s1 = s2 = s3 = 0.f;
                    cur_d = d;
                    qu = *(const uint2*)(Qb + (((size_t)d) << 8) + c0);
                }
            }
            float q0 = lo16(qu.x), q1 = hi16(qu.x);
            float q2 = lo16(qu.y), q3 = hi16(qu.y);
            s0 += gelu_f(lo16(pu[j].x) + q0 + lo16(ru[j].x));
            s1 += gelu_f(hi16(pu[j].x) + q1 + hi16(ru[j].x));
            s2 += gelu_f(lo16(pu[j].y) + q2 + lo16(ru[j].y));
            s3 += gelu_f(hi16(pu[j].y) + q3 + hi16(ru[j].y));
        }
        if (!emitted) {
            F0 = s0; F1 = s1; F2 = s2; F3 = s3;
            lastd = -2;
        } else {
            lastd = cur_d;
        }
    } else {
        int lim = n_e - base;
        if (lim < 0) lim = 0;
        if (lim > 16) lim = 16;
        if (lim == 0) { fd_first = -2; lastd = -2; }
        for (int j = 0; j < lim; ++j) {
            if (j > 0) {
                int d = __builtin_amdgcn_readlane(vdw, j);
                if (d != cur_d) {
                    if (!emitted) {
                        F0 = s0; F1 = s1; F2 = s2; F3 = s3;
                        emitted = 1;
                    } else {
                        float* hp = Hacc + (((size_t)cur_d) << 8) + c0;
                        hp[0] += s0; hp[1] += s1; hp[2] += s2; hp[3] += s3;
                    }
                    s0 = s1 = s2 = s3 = 0.f;
                    cur_d = d;
                    qu = *(const uint2*)(Qb + (((size_t)d) << 8) + c0);
                }
            }
            int s = __builtin_amdgcn_readlane(vsw, j);
            uint2 pv = *(const uint2*)(Pb + (((size_t)s) << 8) + c0);
            int k = base + j;
            int off = (((lane >> 2) ^ ((k >> 2) & 3)) << 4) + ((lane & 3) << 2);
            uint2 rv = *(const uint2*)(tiles + k * 256 + off);
            s0 += gelu_f(lo16(pv.x) + lo16(qu.x) + lo16(rv.x));
            s1 += gelu_f(hi16(pv.x) + hi16(qu.x) + hi16(rv.x));
            s2 += gelu_f(lo16(pv.y) + lo16(qu.y) + lo16(rv.y));
            s3 += gelu_f(hi16(pv.y) + hi16(qu.y) + hi16(rv.y));
        }
        if (lim > 0) {
            if (!emitted) {
                F0 = s0; F1 = s1; F2 = s2; F3 = s3;
                lastd = -2;
            } else {
                lastd = cur_d;
            }
        }
    }

    __syncthreads();  // all waves done reading R tile -> alias as carries

    Fr[w * 256 + c0 + 0] = F0;
    Fr[w * 256 + c0 + 1] = F1;
    Fr[w * 256 + c0 + 2] = F2;
    Fr[w * 256 + c0 + 3] = F3;
    Lr[w * 256 + c0 + 0] = s0;
    Lr[w * 256 + c0 + 1] = s1;
    Lr[w * 256 + c0 + 2] = s2;
    Lr[w * 256 + c0 + 3] = s3;
    if (lane == 0) {
        Cd[w] = fd_first;
        Cd[4 + w] = lastd;
    }
    __syncthreads();

    {
        int ch = threadIdx.x;
        float rv = 0.f;
        int rd = -1;
#pragma unroll
        for (int i = 0; i < 8; ++i) {
            int wi = i >> 1;
            int d = (i & 1) ? Cd[4 + wi] : Cd[wi];
            if (d < 0) continue;
            float v = (i & 1) ? Lr[wi * 256 + ch] : Fr[wi * 256 + ch];
            if (d == rd) {
                rv += v;
            } else {
                if (rd >= 0) {
                    int end = cursor[rd], beg = end - cnt[rd];
                    size_t hidx = (((size_t)rd) << 8) + ch;
                    if (beg >= e_lo && end <= e_hi)
                        Hacc[hidx] += rv;
                    else
                        atomicAdd(&Hacc[hidx], rv);
                }
                rd = d;
                rv = v;
            }
        }
        if (rd >= 0) {
            int end = cursor[rd], beg = end - cnt[rd];
            size_t hidx = (((size_t)rd) << 8) + ch;
            if (beg >= e_lo && end <= e_hi)
                Hacc[hidx] += rv;
            else
                atomicAdd(&Hacc[hidx], rv);
        }
    }
}

// ---------------------------------------------------------------------------
extern "C" void kernel_launch(void* const* d_in, const int* in_sizes, int n_in,
                              void* d_out, int out_size, void* d_ws, size_t ws_size,
                              hipStream_t stream) {
    const float* x     = (const float*)d_in[0];
    const int*   ei    = (const int*)d_in[1];
    const float* ef    = (const float*)d_in[2];
    const float* W_ff1 = (const float*)d_in[3];
    const float* b_ff1 = (const float*)d_in[4];
    const float* W_mp1 = (const float*)d_in[5];
    const float* b_mp1 = (const float*)d_in[6];
    const float* W_mp2 = (const float*)d_in[7];
    const float* b_mp2 = (const float*)d_in[8];
    const float* W_ff2 = (const float*)d_in[9];
    const float* b_ff2 = (const float*)d_in[10];

    const int N = in_sizes[0] / 256;  // 10000
    const int E = in_sizes[1] / 2;    // 320000
    const int* src = ei;
    const int* dst = ei + E;

    // ---- workspace carve (256B-aligned bumps) ----
    char* p = (char*)d_ws;
    unsigned short* Pbuf = (unsigned short*)p;  p += ((size_t)N * 256 * 2 + 255) & ~255ull;
    unsigned short* Qbuf = (unsigned short*)p;  p += ((size_t)N * 256 * 2 + 255) & ~255ull;
    float* Hacc = (float*)p;                    p += ((size_t)N * 256 * 4 + 255) & ~255ull;
    unsigned short* Bp = (unsigned short*)p;    p += (425984ull * 2 + 255) & ~255ull;
    int* cnt    = (int*)p;                      p += ((size_t)N * 4 + 255) & ~255ull;
    int* cursor = (int*)p;                      p += ((size_t)N * 4 + 255) & ~255ull;
    int* perm   = (int*)p;                      p += ((size_t)E * 4 + 255) & ~255ull;
    int* srcs   = (int*)p;                      p += ((size_t)E * 4 + 255) & ~255ull;
    int* dsts   = (int*)p;                      p += ((size_t)E * 4 + 255) & ~255ull;

    unsigned short* Bp_ff1 = Bp + 0;
    unsigned short* Bp_a1  = Bp + 65536;
    unsigned short* Bp_b1  = Bp + 131072;
    unsigned short* Bp_c1  = Bp + 196608;
    unsigned short* Bp_a2  = Bp + 212992;
    unsigned short* Bp_b2  = Bp + 278528;
    unsigned short* Bp_c2  = Bp + 344064;
    unsigned short* Bp_ff2 = Bp + 360448;

    // ---- repack all weights (single dispatch) ----
    repack_all<<<1664, 256, 0, stream>>>(W_ff1, W_mp1, W_mp2, W_ff2, Bp);

    // ---- counting sort of edges by dst (CSR) ----
    zero_i32<<<(N + 255) / 256, 256, 0, stream>>>(cnt, N);
    hist_kernel<<<(E + 255) / 256, 256, 0, stream>>>(dst, cnt, E);
    scan_kernel<<<1, 1024, 0, stream>>>(cnt, cursor, N);
    scatter_kernel<<<(E + 255) / 256, 256, 0, stream>>>(src, dst, cursor, perm, srcs,
                                                        dsts, E);

    int n_tiles = (E + 63) / 64;
    int n_rb = (N + 15) / 16;  // 625

    // ---- layer 1 front: FFN1 + P/Q in one kernel ----
    ffn1pq_kernel<<<n_rb, 64, 0, stream>>>(x, Bp_ff1, b_ff1, Bp_a1, Bp_b1,
                                           b_mp1, Hacc, Pbuf, Qbuf, N);
    fused_kernel<<<n_tiles, 256, 0, stream>>>(
        ef, perm, srcs, dsts, Bp_c1, Pbuf, Qbuf, cursor, cnt, Hacc, E);

    // ---- layer 2 front: P/Q from f32 Hacc (no finalize) ----
    pq2_kernel<<<n_rb, 64, 0, stream>>>(Hacc, Bp_a2, Bp_b2, b_mp2, Pbuf, Qbuf, N);
    fused_kernel<<<n_tiles, 256, 0, stream>>>(
        ef, perm, srcs, dsts, Bp_c2, Pbuf, Qbuf, cursor, cnt, Hacc, E);

    // ---- FFN2: out = x + bf16(Hacc)@W_ff2 + b ----
    dim3 gN((N + 63) / 64, 4);
    gemm_kernel<<<gN, 256, 0, stream>>>(Hacc, 1, N, 256, Bp_ff2, b_ff2, x,
                                        nullptr, (float*)d_out, 0);
}

// Round 12
// 413.067 us; speedup vs baseline: 1.2399x; 1.2399x over previous
//
#include <hip/hip_runtime.h>

// ---------------------------------------------------------------------------
// ResBlock GNN layer on MI355X (gfx950). ALL tensors fp32.
//   h  = gelu(x @ W_ff1 + b)
//   h += seg_sum(gelu(P[src]+Q[dst]+R_e+b_mp)), P=h@Wa, Q=h@Wb, R=ef@Wc  (x2)
//   out = x + h @ W_ff2 + b
// R17b: resubmit of R17 (GPU acquisition timeout, kernel never ran).
// Revert R16's 64-thread fusion (96us: 2.4 waves/CU, VALU 2.5%) back to the
// R15 structure (measured best, 412.7us), keeping the ONE sound R16 idea:
// pqf_kernel reads the A-operand as f32 from Hacc (converts in flight,
// proven pq shape grid(157,8)x256thr) for BOTH layers ->
//   - finalize_h dispatch deleted;
//   - h_bf buffer deleted (FFN1 gemm writes only Hacc);
//   - 12 -> 10 dispatches. Numerics bit-identical (same RNE f2bf points).
// fused_kernel = R15 verbatim (proven 92us).
// ---------------------------------------------------------------------------

typedef __attribute__((ext_vector_type(8))) short short8;
typedef __attribute__((ext_vector_type(4))) float f32x4;

#define HD __device__ __forceinline__

HD unsigned short f2bf(float f) {
    unsigned int u = __float_as_uint(f);
    return (unsigned short)((u + 0x7fffu + ((u >> 16) & 1u)) >> 16);  // RNE
}
HD float lo16(unsigned int u) { return __uint_as_float(u << 16); }
HD float hi16(unsigned int u) { return __uint_as_float(u & 0xffff0000u); }
HD float bf2f(unsigned short u) { return __uint_as_float(((unsigned int)u) << 16); }

// gelu tanh-approx via sigmoid identity: 0.5(1+tanh(z)) == sigmoid(2z).
HD float gelu_f(float x) {
    float u = x * (-1.5957691216057308f - 0.07135481627f * (x * x));
    return x * __builtin_amdgcn_rcpf(1.f + __expf(u));
}

// ---------------------------------------------------------------------------
// All 8 weight repacks in one dispatch.
// ---------------------------------------------------------------------------
__global__ void repack_all(const float* __restrict__ Wff1,
                           const float* __restrict__ Wmp1,
                           const float* __restrict__ Wmp2,
                           const float* __restrict__ Wff2,
                           unsigned short* __restrict__ Bp) {
    const int begs[9] = {0, 65536, 131072, 196608, 212992, 278528, 344064,
                         360448, 425984};
    const int srcid[8] = {0, 1, 1, 1, 2, 2, 2, 3};
    const int rowoff[8] = {0, 0, 256, 512, 0, 256, 512, 0};
    int i = blockIdx.x * 256 + threadIdx.x;
    if (i >= 425984) return;
    int s = 0;
#pragma unroll
    for (int k = 1; k < 8; ++k)
        if (i >= begs[k]) s = k;
    const float* Ws[4] = {Wff1, Wmp1, Wmp2, Wff2};
    const float* B = Ws[srcid[s]];
    int local = i - begs[s];
    int k = local >> 8, n = local & 255;
    int kb = k >> 5, kr = k & 31;
    int quad = kr >> 3, j = kr & 7;
    int lane = quad * 16 + (n & 15);
    int nt = n >> 4;
    Bp[begs[s] + ((((kb * 16 + nt) * 64) + lane) << 3) + j] =
        f2bf(B[(size_t)(rowoff[s] + k) * 256 + n]);
}

// ---------------------------------------------------------------------------
// General LDS-free bf16 MFMA GEMM (64x64 tile, grid (ceil(M/64),4)).
// ---------------------------------------------------------------------------
__global__ __launch_bounds__(256) void gemm_kernel(
    const void* __restrict__ Av, int a_is_f32, int M, int K,
    const unsigned short* __restrict__ Bp,
    const float* __restrict__ bias, const float* __restrict__ resid,
    unsigned short* __restrict__ Cb, float* __restrict__ Cf, int do_gelu) {
    int lane = threadIdx.x & 63;
    int w = threadIdx.x >> 6;
    int row0 = blockIdx.x * 64 + w * 16;
    int n0 = blockIdx.y * 64;
    int m15 = lane & 15, quad = lane >> 4;

    int arow = row0 + m15;
    if (arow > M - 1) arow = M - 1;

    f32x4 acc[4] = {{0,0,0,0},{0,0,0,0},{0,0,0,0},{0,0,0,0}};
    const float* Af = (const float*)Av + (size_t)arow * K + quad * 8;
    const unsigned short* Ab = (const unsigned short*)Av + (size_t)arow * K + quad * 8;

    for (int kt = 0; kt < K; kt += 32) {
        short8 a;
        if (a_is_f32) {
            f32x4 lo = *(const f32x4*)(Af + kt);
            f32x4 hi = *(const f32x4*)(Af + kt + 4);
#pragma unroll
            for (int j = 0; j < 4; ++j) {
                a[j] = (short)f2bf(lo[j]);
                a[j + 4] = (short)f2bf(hi[j]);
            }
        } else {
            a = *(const short8*)(Ab + kt);
        }
        const unsigned short* bbase =
            Bp + ((((size_t)(kt >> 5) * 16 + (n0 >> 4)) * 64 + lane) << 3);
#pragma unroll
        for (int nt = 0; nt < 4; ++nt) {
            short8 b = *(const short8*)(bbase + nt * 64 * 8);
            acc[nt] = __builtin_amdgcn_mfma_f32_16x16x32_bf16(a, b, acc[nt], 0, 0, 0);
        }
    }

#pragma unroll
    for (int nt = 0; nt < 4; ++nt) {
        int col = n0 + nt * 16 + m15;
        float bv = bias ? bias[col] : 0.f;
#pragma unroll
        for (int r = 0; r < 4; ++r) {
            int row = row0 + quad * 4 + r;
            if (row < M) {
                float v = acc[nt][r] + bv;
                if (do_gelu) v = gelu_f(v);
                size_t idx = (size_t)row * 256 + col;
                if (resid) v += resid[idx];
                if (Cb) Cb[idx] = f2bf(v);
                if (Cf) Cf[idx] = v;
            }
        }
    }
}

// ---------------------------------------------------------------------------
// P and Q in one dispatch from f32 A (Hacc): grid ((M+63)/64, 8);
// y<4 -> P cols, y>=4 -> Q cols. Converts A to bf16 in flight (same RNE).
// ---------------------------------------------------------------------------
__global__ __launch_bounds__(256) void pqf_kernel(
    const float* __restrict__ A, int M,
    const unsigned short* __restrict__ BpA, const unsigned short* __restrict__ BpB,
    const float* __restrict__ qbias,
    unsigned short* __restrict__ Pb, unsigned short* __restrict__ Qb) {
    int lane = threadIdx.x & 63;
    int w = threadIdx.x >> 6;
    int row0 = blockIdx.x * 64 + w * 16;
    int isQ = blockIdx.y >> 2;
    int n0 = (blockIdx.y & 3) * 64;
    const unsigned short* Bp = isQ ? BpB : BpA;
    unsigned short* out = isQ ? Qb : Pb;
    int m15 = lane & 15, quad = lane >> 4;

    int arow = row0 + m15;
    if (arow > M - 1) arow = M - 1;
    const float* Af = A + (size_t)arow * 256 + quad * 8;

    f32x4 acc[4] = {{0,0,0,0},{0,0,0,0},{0,0,0,0},{0,0,0,0}};
    for (int kt = 0; kt < 256; kt += 32) {
        f32x4 lo = *(const f32x4*)(Af + kt);
        f32x4 hi = *(const f32x4*)(Af + kt + 4);
        short8 a;
#pragma unroll
        for (int j = 0; j < 4; ++j) {
            a[j] = (short)f2bf(lo[j]);
            a[j + 4] = (short)f2bf(hi[j]);
        }
        const unsigned short* bbase =
            Bp + ((((size_t)(kt >> 5) * 16 + (n0 >> 4)) * 64 + lane) << 3);
#pragma unroll
        for (int nt = 0; nt < 4; ++nt) {
            short8 b = *(const short8*)(bbase + nt * 64 * 8);
            acc[nt] = __builtin_amdgcn_mfma_f32_16x16x32_bf16(a, b, acc[nt], 0, 0, 0);
        }
    }

#pragma unroll
    for (int nt = 0; nt < 4; ++nt) {
        int col = n0 + nt * 16 + m15;
        float bv = isQ ? qbias[col] : 0.f;
#pragma unroll
        for (int r = 0; r < 4; ++r) {
            int row = row0 + quad * 4 + r;
            if (row < M) out[(size_t)row * 256 + col] = f2bf(acc[nt][r] + bv);
        }
    }
}

// ---------------------------------------------------------------------------
// Counting sort by dst: zero -> histogram -> single-block scan -> scatter.
// ---------------------------------------------------------------------------
__global__ void zero_i32(int* __restrict__ p, int n) {
    int i = blockIdx.x * 256 + threadIdx.x;
    if (i < n) p[i] = 0;
}
__global__ void hist_kernel(const int* __restrict__ dst, int* __restrict__ cnt, int E) {
    int e = blockIdx.x * 256 + threadIdx.x;
    if (e < E) atomicAdd(&cnt[dst[e]], 1);
}
__global__ __launch_bounds__(1024) void scan_kernel(const int* __restrict__ cnt,
                                                    int* __restrict__ cursor, int N) {
    __shared__ int part[1024];
    int tid = threadIdx.x;
    int per = (N + 1023) / 1024;
    int lo = tid * per;
    int s = 0;
    for (int j = 0; j < per; ++j) {
        int idx = lo + j;
        if (idx < N) s += cnt[idx];
    }
    part[tid] = s;
    __syncthreads();
    for (int off = 1; off < 1024; off <<= 1) {
        int t = (tid >= off) ? part[tid - off] : 0;
        __syncthreads();
        part[tid] += t;
        __syncthreads();
    }
    int run = (tid > 0) ? part[tid - 1] : 0;
    for (int j = 0; j < per; ++j) {
        int idx = lo + j;
        if (idx < N) {
            cursor[idx] = run;
            run += cnt[idx];
        }
    }
}
__global__ void scatter_kernel(const int* __restrict__ src, const int* __restrict__ dst,
                               int* __restrict__ cursor, int* __restrict__ perm,
                               int* __restrict__ srcs, int* __restrict__ dsts, int E) {
    int e = blockIdx.x * 256 + threadIdx.x;
    if (e < E) {
        int d = dst[e];
        int pos = atomicAdd(&cursor[d], 1);
        perm[pos] = e;
        srcs[pos] = src[e];
        dsts[pos] = d;
    }
}

// ---------------------------------------------------------------------------
// FUSED edge kernel (R15, unchanged). Block = 256 thr = one 64-edge tile.
// Phase 1: R[64x256] -> swizzled LDS (wave w: rows w*16..+15, acc[16]).
// Phase 2: wave w walks its own 16 rows, 4 ch/lane uint2, 16-deep prefetch.
// Merge: carry chain in LDS (aliased), interior RMW / boundary atomicAdd.
// ---------------------------------------------------------------------------
__global__ __launch_bounds__(256, 4) void fused_kernel(
    const float* __restrict__ ef, const int* __restrict__ perm,
    const int* __restrict__ srcs, const int* __restrict__ dsts,
    const unsigned short* __restrict__ BpC,
    const unsigned short* __restrict__ Pb, const unsigned short* __restrict__ Qb,
    const int* __restrict__ cursor, const int* __restrict__ cnt,
    float* __restrict__ Hacc, int E) {
    __shared__ unsigned short tiles[64 * 256];  // 32 KB R tile (swizzled)
    float* Fr = (float*)tiles;            // [4][256] carry (aliased later)
    float* Lr = Fr + 4 * 256;             // [4][256]
    int* Cd = (int*)(Lr + 4 * 256);       // [8]

    int lane = threadIdx.x & 63;
    int w = threadIdx.x >> 6;  // 0..3
    int e_lo = blockIdx.x * 64;
    int n_e = E - e_lo;
    if (n_e > 64) n_e = 64;
    int e_hi = e_lo + n_e;
    int base = w * 16;
    int m15 = lane & 15, quad = lane >> 4;
    int c0 = lane << 2;

    int myi = base + (lane & 15);
    int mye = e_lo + myi;
    if (mye > E - 1) mye = E - 1;
    int vsw = srcs[mye];
    int vdw = dsts[mye];

    int cur_d = -2;
    uint2 qu = {0u, 0u};
    if (base < n_e) {
        cur_d = __builtin_amdgcn_readlane(vdw, 0);
        qu = *(const uint2*)(Qb + (((size_t)cur_d) << 8) + c0);
    }
    int fd_first = cur_d;

    // ---- Phase 1: rgemm body, wave w -> rows base..base+15 ----
    {
        int ar = e_lo + base + m15;
        if (ar > E - 1) ar = E - 1;
        int g = perm[ar];
        const float* A = ef + (size_t)g * 64 + quad * 8;

        f32x4 acc[16];
#pragma unroll
        for (int i = 0; i < 16; ++i) acc[i] = {0.f, 0.f, 0.f, 0.f};

#pragma unroll
        for (int kb = 0; kb < 2; ++kb) {
            f32x4 lo = *(const f32x4*)(A + kb * 32);
            f32x4 hi = *(const f32x4*)(A + kb * 32 + 4);
            short8 a;
#pragma unroll
            for (int j = 0; j < 4; ++j) {
                a[j] = (short)f2bf(lo[j]);
                a[j + 4] = (short)f2bf(hi[j]);
            }
            const unsigned short* bb = BpC + (((size_t)kb * 16 * 64 + lane) << 3);
#pragma unroll
            for (int nt = 0; nt < 16; ++nt) {
                short8 b = *(const short8*)(bb + (size_t)nt * 64 * 8);
                acc[nt] = __builtin_amdgcn_mfma_f32_16x16x32_bf16(a, b, acc[nt], 0, 0, 0);
            }
        }

#pragma unroll
        for (int nt = 0; nt < 16; ++nt) {
            int colp = ((nt ^ quad) << 4) + m15;
#pragma unroll
            for (int r = 0; r < 4; ++r) {
                int row = base + quad * 4 + r;
                tiles[row * 256 + colp] = f2bf(acc[nt][r]);
            }
        }
    }
    // NO barrier: wave w's phase 2 reads only rows it wrote itself.

    // ---- Phase 2: walk own 16 rows, 4 ch/lane ----
    float s0 = 0.f, s1 = 0.f, s2 = 0.f, s3 = 0.f;
    float F0 = 0.f, F1 = 0.f, F2 = 0.f, F3 = 0.f;
    int lastd = -2;
    int emitted = 0;

    if (n_e == 64) {
        uint2 pu[16], ru[16];
#pragma unroll
        for (int j = 0; j < 16; ++j) {
            int s = __builtin_amdgcn_readlane(vsw, j);
            pu[j] = *(const uint2*)(Pb + (((size_t)s) << 8) + c0);
            int k = base + j;
            int off = (((lane >> 2) ^ ((j >> 2) & 3)) << 4) + ((lane & 3) << 2);
            ru[j] = *(const uint2*)(tiles + k * 256 + off);
        }
#pragma unroll
        for (int j = 0; j < 16; ++j) {
            if (j > 0) {
                int d = __builtin_amdgcn_readlane(vdw, j);
                if (d != cur_d) {
                    if (!emitted) {
                        F0 = s0; F1 = s1; F2 = s2; F3 = s3;
                        emitted = 1;
                    } else {
                        float* hp = Hacc + (((size_t)cur_d) << 8) + c0;
                        hp[0] += s0; hp[1] += s1; hp[2] += s2; hp[3] += s3;
                    }
                    s0 = s1 = s2 = s3 = 0.f;
                    cur_d = d;
                    qu = *(const uint2*)(Qb + (((size_t)d) << 8) + c0);
                }
            }
            float q0 = lo16(qu.x), q1 = hi16(qu.x);
            float q2 = lo16(qu.y), q3 = hi16(qu.y);
            s0 += gelu_f(lo16(pu[j].x) + q0 + lo16(ru[j].x));
            s1 += gelu_f(hi16(pu[j].x) + q1 + hi16(ru[j].x));
            s2 += gelu_f(lo16(pu[j].y) + q2 + lo16(ru[j].y));
            s3 += gelu_f(hi16(pu[j].y) + q3 + hi16(ru[j].y));
        }
        if (!emitted) {
            F0 = s0; F1 = s1; F2 = s2; F3 = s3;
            lastd = -2;
        } else {
            lastd = cur_d;
        }
    } else {
        int lim = n_e - base;
        if (lim < 0) lim = 0;
        if (lim > 16) lim = 16;
        if (lim == 0) { fd_first = -2; lastd = -2; }
        for (int j = 0; j < lim; ++j) {
            if (j > 0) {
                int d = __builtin_amdgcn_readlane(vdw, j);
                if (d != cur_d) {
                    if (!emitted) {
                        F0 = s0; F1 = s1; F2 = s2; F3 = s3;
                        emitted = 1;
                    } else {
                        float* hp = Hacc + (((size_t)cur_d) << 8) + c0;
                        hp[0] += s0; hp[1] += s1; hp[2] += s2; hp[3] += s3;
                    }
                    s0 = s1 = s2 = s3 = 0.f;
                    cur_d = d;
                    qu = *(const uint2*)(Qb + (((size_t)d) << 8) + c0);
                }
            }
            int s = __builtin_amdgcn_readlane(vsw, j);
            uint2 pv = *(const uint2*)(Pb + (((size_t)s) << 8) + c0);
            int k = base + j;
            int off = (((lane >> 2) ^ ((k >> 2) & 3)) << 4) + ((lane & 3) << 2);
            uint2 rv = *(const uint2*)(tiles + k * 256 + off);
            s0 += gelu_f(lo16(pv.x) + lo16(qu.x) + lo16(rv.x));
            s1 += gelu_f(hi16(pv.x) + hi16(qu.x) + hi16(rv.x));
            s2 += gelu_f(lo16(pv.y) + lo16(qu.y) + lo16(rv.y));
            s3 += gelu_f(hi16(pv.y) + hi16(qu.y) + hi16(rv.y));
        }
        if (lim > 0) {
            if (!emitted) {
                F0 = s0; F1 = s1; F2 = s2; F3 = s3;
                lastd = -2;
            } else {
                lastd = cur_d;
            }
        }
    }

    __syncthreads();  // all waves done reading R tile -> alias as carries

    Fr[w * 256 + c0 + 0] = F0;
    Fr[w * 256 + c0 + 1] = F1;
    Fr[w * 256 + c0 + 2] = F2;
    Fr[w * 256 + c0 + 3] = F3;
    Lr[w * 256 + c0 + 0] = s0;
    Lr[w * 256 + c0 + 1] = s1;
    Lr[w * 256 + c0 + 2] = s2;
    Lr[w * 256 + c0 + 3] = s3;
    if (lane == 0) {
        Cd[w] = fd_first;
        Cd[4 + w] = lastd;
    }
    __syncthreads();

    {
        int ch = threadIdx.x;
        float rv = 0.f;
        int rd = -1;
#pragma unroll
        for (int i = 0; i < 8; ++i) {
            int wi = i >> 1;
            int d = (i & 1) ? Cd[4 + wi] : Cd[wi];
            if (d < 0) continue;
            float v = (i & 1) ? Lr[wi * 256 + ch] : Fr[wi * 256 + ch];
            if (d == rd) {
                rv += v;
            } else {
                if (rd >= 0) {
                    int end = cursor[rd], beg = end - cnt[rd];
                    size_t hidx = (((size_t)rd) << 8) + ch;
                    if (beg >= e_lo && end <= e_hi)
                        Hacc[hidx] += rv;
                    else
                        atomicAdd(&Hacc[hidx], rv);
                }
                rd = d;
                rv = v;
            }
        }
        if (rd >= 0) {
            int end = cursor[rd], beg = end - cnt[rd];
            size_t hidx = (((size_t)rd) << 8) + ch;
            if (beg >= e_lo && end <= e_hi)
                Hacc[hidx] += rv;
            else
                atomicAdd(&Hacc[hidx], rv);
        }
    }
}

// ---------------------------------------------------------------------------
extern "C" void kernel_launch(void* const* d_in, const int* in_sizes, int n_in,
                              void* d_out, int out_size, void* d_ws, size_t ws_size,
                              hipStream_t stream) {
    const float* x     = (const float*)d_in[0];
    const int*   ei    = (const int*)d_in[1];
    const float* ef    = (const float*)d_in[2];
    const float* W_ff1 = (const float*)d_in[3];
    const float* b_ff1 = (const float*)d_in[4];
    const float* W_mp1 = (const float*)d_in[5];
    const float* b_mp1 = (const float*)d_in[6];
    const float* W_mp2 = (const float*)d_in[7];
    const float* b_mp2 = (const float*)d_in[8];
    const float* W_ff2 = (const float*)d_in[9];
    const float* b_ff2 = (const float*)d_in[10];

    const int N = in_sizes[0] / 256;  // 10000
    const int E = in_sizes[1] / 2;    // 320000
    const int* src = ei;
    const int* dst = ei + E;

    // ---- workspace carve (256B-aligned bumps) ----
    char* p = (char*)d_ws;
    unsigned short* Pbuf = (unsigned short*)p;  p += ((size_t)N * 256 * 2 + 255) & ~255ull;
    unsigned short* Qbuf = (unsigned short*)p;  p += ((size_t)N * 256 * 2 + 255) & ~255ull;
    float* Hacc = (float*)p;                    p += ((size_t)N * 256 * 4 + 255) & ~255ull;
    unsigned short* Bp = (unsigned short*)p;    p += (425984ull * 2 + 255) & ~255ull;
    int* cnt    = (int*)p;                      p += ((size_t)N * 4 + 255) & ~255ull;
    int* cursor = (int*)p;                      p += ((size_t)N * 4 + 255) & ~255ull;
    int* perm   = (int*)p;                      p += ((size_t)E * 4 + 255) & ~255ull;
    int* srcs   = (int*)p;                      p += ((size_t)E * 4 + 255) & ~255ull;
    int* dsts   = (int*)p;                      p += ((size_t)E * 4 + 255) & ~255ull;

    unsigned short* Bp_ff1 = Bp + 0;
    unsigned short* Bp_a1  = Bp + 65536;
    unsigned short* Bp_b1  = Bp + 131072;
    unsigned short* Bp_c1  = Bp + 196608;
    unsigned short* Bp_a2  = Bp + 212992;
    unsigned short* Bp_b2  = Bp + 278528;
    unsigned short* Bp_c2  = Bp + 344064;
    unsigned short* Bp_ff2 = Bp + 360448;

    // ---- repack all weights (single dispatch) ----
    repack_all<<<1664, 256, 0, stream>>>(W_ff1, W_mp1, W_mp2, W_ff2, Bp);

    // ---- counting sort of edges by dst (CSR) ----
    zero_i32<<<(N + 255) / 256, 256, 0, stream>>>(cnt, N);
    hist_kernel<<<(E + 255) / 256, 256, 0, stream>>>(dst, cnt, E);
    scan_kernel<<<1, 1024, 0, stream>>>(cnt, cursor, N);
    scatter_kernel<<<(E + 255) / 256, 256, 0, stream>>>(src, dst, cursor, perm, srcs,
                                                        dsts, E);

    dim3 gN((N + 63) / 64, 4);
    dim3 gPQ((N + 63) / 64, 8);
    int n_tiles = (E + 63) / 64;

    // ---- FFN1: Hacc = gelu(x@W_ff1 + b)  (f32 only; no bf16 copy) ----
    gemm_kernel<<<gN, 256, 0, stream>>>(x, 1, N, 256, Bp_ff1, b_ff1, nullptr,
                                        nullptr, Hacc, 1);

    const unsigned short* Bp_a[2] = {Bp_a1, Bp_a2};
    const unsigned short* Bp_b[2] = {Bp_b1, Bp_b2};
    const unsigned short* Bp_c[2] = {Bp_c1, Bp_c2};
    const float* bmp[2] = {b_mp1, b_mp2};

    for (int l = 0; l < 2; ++l) {
        pqf_kernel<<<gPQ, 256, 0, stream>>>(Hacc, N, Bp_a[l], Bp_b[l], bmp[l],
                                            Pbuf, Qbuf);
        fused_kernel<<<n_tiles, 256, 0, stream>>>(
            ef, perm, srcs, dsts, Bp_c[l], Pbuf, Qbuf, cursor, cnt, Hacc, E);
    }

    // ---- FFN2: out = x + bf16(Hacc)@W_ff2 + b ----
    gemm_kernel<<<gN, 256, 0, stream>>>(Hacc, 1, N, 256, Bp_ff2, b_ff2, x,
                                        nullptr, (float*)d_out, 0);
}